// Round 7
// baseline (16026.064 us; speedup 1.0000x reference)
//
#include <hip/hip_runtime.h>
#include <stdint.h>

typedef __attribute__((ext_vector_type(4))) float f32x4;
typedef __attribute__((ext_vector_type(8))) short s16x8;

// ---------------- workspace layout (bytes) ----------------
#define XPK_OFF  0ull
#define WL0_OFF  134217728ull
#define WL1_OFF  176160768ull
#define H0_OFF   218103808ull
#define H1_OFF   218628096ull
#define C0_OFF   219152384ull
#define C1_OFF   219414528ull
#define WS_NEED  219676672ull

#define OUT_HF 33554432
#define OUT_CF 33685504

static __device__ __forceinline__ float bf2f(unsigned short u){
  unsigned int x = ((unsigned int)u) << 16;
  return __builtin_bit_cast(float, x);
}
static __device__ __forceinline__ unsigned short f2bf(float f){
  unsigned int x = __builtin_bit_cast(unsigned int, f);
  x = x + 0x7FFFu + ((x >> 16) & 1u);   // RNE
  return (unsigned short)(x >> 16);
}
static __device__ __forceinline__ float sigm(float x){ return 1.f/(1.f + __expf(-x)); }
static __device__ __forceinline__ float tanh_(float x){ return 1.f - 2.f/(__expf(2.f*x) + 1.f); }

// ---------------- pack kernels (unchanged from validated round 4) ----------------
__global__ void k_pack_x(const float* __restrict__ x, unsigned short* __restrict__ xpk){
  int tid = blockIdx.x*256 + threadIdx.x;        // 4,194,304 threads
  int row = tid >> 7, k8 = tid & 127;
  int t = row >> 6, m = row & 63;
  const float* src = x + (long)row*1024 + k8*8;
  int frag = (k8>>2)*4 + (m>>4);
  int ln   = (m&15) + ((k8&3)<<4);
  unsigned short* dst = xpk + (long)t*131072 + frag*512 + ln*8;
  s16x8 hi, lo;
  #pragma unroll
  for (int i=0;i<8;++i){
    float v = src[i];
    unsigned short h = f2bf(v);
    hi[i] = (short)h;
    lo[i] = (short)f2bf(v - bf2f(h));
  }
  *(s16x8*)dst = hi;
  *(s16x8*)(dst + 65536) = lo;
}

__global__ void k_pack_w(const float* __restrict__ wall, const float* __restrict__ wt,
                         unsigned short* __restrict__ dst, int layer){
  int tid = blockIdx.x*256 + threadIdx.x;        // 1,310,720 threads
  int grp = tid >> 12;                           // 0..319
  int fi  = (tid >> 6) & 63;                     // k/32
  int slot= tid & 63;
  int jj  = slot & 15;
  int k   = (fi*4 + (slot>>4)) * 8;
  int c   = grp / 5, gi = grp % 5;
  const float* src = nullptr;
  bool zero = false;
  if (gi < 4){
    int row = gi*1024 + c*16 + jj;
    int sk = (layer==0) ? ((k < 1024) ? 1024 + k : k - 1024) : k;
    src = wall + (long)row*2048 + sk;
  } else {
    if (layer == 0){
      if (k >= 1024) src = wt + (long)(c*16+jj)*1024 + (k-1024); else zero = true;
    } else {
      if (k < 1024)  src = wt + (long)(c*16+jj)*1024 + k;        else zero = true;
    }
  }
  s16x8 hi, lo;
  #pragma unroll
  for (int i=0;i<8;++i){
    float v = zero ? 0.f : src[i];
    unsigned short h = f2bf(v);
    hi[i] = (short)h;
    lo[i] = (short)f2bf(v - bf2f(h));
  }
  long base = (long)(grp*64 + fi)*512 + slot*8;
  *(s16x8*)(dst + base) = hi;
  *(s16x8*)(dst + 10485760 + base) = lo;
}

// ---------------- per-step kernel ----------------
// 128 blocks: layer = bid>>6, c = bid&63 (16 output cols each, ALL 64 batch rows).
// Every weight byte is read by exactly ONE block per step (no duplication).
// 8 waves (512 thr): wave w covers K-slice (w&3)*256 of source (w<4 ? A1 : A2);
// partials combined via 4-buffer LDS tree (w0-3 write, w4-7 add, cell sums 4).
__global__ __launch_bounds__(512, 2) void k_step(
    const unsigned short* __restrict__ xpk,
    const unsigned short* __restrict__ wl0,
    const unsigned short* __restrict__ wl1,
    unsigned short* __restrict__ h0pk,
    unsigned short* __restrict__ h1pk,
    float* __restrict__ c0, float* __restrict__ c1,
    const float* __restrict__ ball0, const float* __restrict__ bt0,
    const float* __restrict__ ball1, const float* __restrict__ bt1,
    float* __restrict__ out, int s)
{
  __shared__ float R[4][64*84];        // 86,016 B (gfx950: 160 KB/CU, 1 block/CU)
  const int bid = blockIdx.x;
  const int layer = bid >> 6;
  const int c = bid & 63;
  if (layer == 0 && s >= 512) return;
  if (layer == 1 && s == 0) return;
  const int tid = threadIdx.x;
  const int lane = tid & 63, w = tid >> 6;   // w in [0,8)

  // ---- GEMM phase: 64x80 tile over this wave's K-eighth (256), bf16x3 ----
  f32x4 acc[4][5];
  #pragma unroll
  for (int a=0;a<4;++a)
    #pragma unroll
    for (int b=0;b<5;++b) acc[a][b] = (f32x4){0.f,0.f,0.f,0.f};
  {
    const unsigned short *A1, *A2, *W;
    bool use1, use2;
    if (layer == 0){
      A1 = h0pk + (size_t)((s+1)&1)*131072;   // h0[s-1]
      A2 = xpk  + (size_t)s*131072;           // x[s]
      W  = wl0;  use1 = (s > 0); use2 = true;
    } else {
      A1 = h0pk + (size_t)((s+1)&1)*131072;   // h0[s-1]
      A2 = h1pk + (size_t)(s&1)*131072;       // h1[s-2]
      W  = wl1;  use1 = true; use2 = (s >= 2);
    }
    const s16x8* Abase = (const s16x8*)((w < 4) ? A1 : A2);
    const bool  useA   = (w < 4) ? use1 : use2;
    const s16x8* Bv    = (const s16x8*)W;
    const int a0 = (w & 3)*32;                       // A frag base (K-quarter of its source)
    const int b0 = c*320 + (w>>2)*32 + (w&3)*8;      // B fi base
    // tx weight block is structurally zero in: L0 h-half (w<4); L1 h1-half (w>=4)
    const bool doTx = (layer == 0) ? (w >= 4) : (w < 4);

    const s16x8 zz = {0,0,0,0,0,0,0,0};
    s16x8 ah[2][4], al[2][4], bh[2][5], bl[2][5];
    auto ldfr = [&](int buf, int ks){
      #pragma unroll
      for (int mf=0; mf<4; ++mf){
        int f = (a0 + ks*4 + mf)*64 + lane;
        ah[buf][mf] = useA ? Abase[f] : zz;
        al[buf][mf] = useA ? Abase[8192 + f] : zz;
      }
      #pragma unroll
      for (int nf=0; nf<4; ++nf){
        int f = (b0 + nf*64 + ks)*64 + lane;
        bh[buf][nf] = Bv[f];
        bl[buf][nf] = Bv[1310720 + f];
      }
      if (doTx){
        int f = (b0 + 4*64 + ks)*64 + lane;
        bh[buf][4] = Bv[f];
        bl[buf][4] = Bv[1310720 + f];
      }
    };
    ldfr(0, 0);
    #pragma unroll
    for (int ks=0; ks<8; ++ks){
      const int cur = ks & 1;
      if (ks < 7) ldfr(cur ^ 1, ks + 1);
      #pragma unroll
      for (int mf=0; mf<4; ++mf)
        #pragma unroll
        for (int nf=0; nf<4; ++nf){
          acc[mf][nf] = __builtin_amdgcn_mfma_f32_16x16x32_bf16(ah[cur][mf], bh[cur][nf], acc[mf][nf], 0, 0, 0);
          acc[mf][nf] = __builtin_amdgcn_mfma_f32_16x16x32_bf16(al[cur][mf], bh[cur][nf], acc[mf][nf], 0, 0, 0);
          acc[mf][nf] = __builtin_amdgcn_mfma_f32_16x16x32_bf16(ah[cur][mf], bl[cur][nf], acc[mf][nf], 0, 0, 0);
        }
      if (doTx){
        #pragma unroll
        for (int mf=0; mf<4; ++mf){
          acc[mf][4] = __builtin_amdgcn_mfma_f32_16x16x32_bf16(ah[cur][mf], bh[cur][4], acc[mf][4], 0, 0, 0);
          acc[mf][4] = __builtin_amdgcn_mfma_f32_16x16x32_bf16(al[cur][mf], bh[cur][4], acc[mf][4], 0, 0, 0);
          acc[mf][4] = __builtin_amdgcn_mfma_f32_16x16x32_bf16(ah[cur][mf], bl[cur][4], acc[mf][4], 0, 0, 0);
        }
      }
    }
  }

  // ---- reduce: 4-buffer non-atomic tree (w0-3 write, w4-7 add) ----
  {
    float* Rw = R[w & 3];
    if (w < 4){
      #pragma unroll
      for (int mf=0; mf<4; ++mf)
        #pragma unroll
        for (int nf=0; nf<5; ++nf)
          #pragma unroll
          for (int r=0; r<4; ++r){
            int m = mf*16 + (lane>>4)*4 + r;
            int n = nf*16 + (lane&15);
            Rw[m*84 + n] = acc[mf][nf][r];
          }
    }
    __syncthreads();
    if (w >= 4){
      #pragma unroll
      for (int mf=0; mf<4; ++mf)
        #pragma unroll
        for (int nf=0; nf<5; ++nf)
          #pragma unroll
          for (int r=0; r<4; ++r){
            int m = mf*16 + (lane>>4)*4 + r;
            int n = nf*16 + (lane&15);
            Rw[m*84 + n] += acc[mf][nf][r];
          }
    }
    __syncthreads();
  }

  // ---- cell phase (64 rows x 16 cols = 1024 items over 512 threads) ----
  const int e = (layer == 0) ? s : s - 1;
  const float* ball = layer ? ball1 : ball0;
  const float* bt   = layer ? bt1   : bt0;
  float* cs = layer ? c1 : c0;
  unsigned short* hp = (layer ? h1pk : h0pk) + (size_t)(e&1)*131072;

  #pragma unroll
  for (int it=0; it<2; ++it){
    int idx = it*512 + tid;
    int m = idx >> 4, jj = idx & 15;
    int j = c*16 + jj;
    float pre[4];
    #pragma unroll
    for (int g=0; g<4; ++g)
      pre[g] = R[0][m*84 + g*16 + jj] + R[1][m*84 + g*16 + jj]
             + R[2][m*84 + g*16 + jj] + R[3][m*84 + g*16 + jj] + ball[g*1024 + j];
    float tx = R[0][m*84 + 64 + jj] + R[1][m*84 + 64 + jj]
             + R[2][m*84 + 64 + jj] + R[3][m*84 + 64 + jj] + bt[j];
    float ii = sigm(pre[0]), ff = sigm(pre[1]), oo = sigm(pre[2]);
    float gt = tanh_(tx * pre[3]);
    float cold = (e == 0) ? 0.f : cs[m*1024 + j];
    float cc = ff*cold + ii*gt;
    cs[m*1024 + j] = cc;
    float hh = oo*tanh_(cc);
    int fr = (j>>5)*4 + (m>>4);
    int ln = (m&15) + (((j>>3)&3)<<4);
    unsigned short hb = f2bf(hh);
    hp[fr*512 + ln*8 + (j&7)] = hb;
    hp[65536 + fr*512 + ln*8 + (j&7)] = f2bf(hh - bf2f(hb));
    if (layer){
      out[(size_t)e*65536 + m*1024 + j] = hh;
      if (e == 511){ out[OUT_HF + 65536 + m*1024 + j] = hh; out[OUT_CF + 65536 + m*1024 + j] = cc; }
    } else if (e == 511){
      out[OUT_HF + m*1024 + j] = hh; out[OUT_CF + m*1024 + j] = cc;
    }
  }
}

extern "C" void kernel_launch(void* const* d_in, const int* in_sizes, int n_in,
                              void* d_out, int out_size, void* d_ws, size_t ws_size,
                              hipStream_t stream)
{
  (void)in_sizes; (void)n_in;
  const float* x     = (const float*)d_in[0];
  const float* wall0 = (const float*)d_in[1];
  const float* ball0 = (const float*)d_in[2];
  const float* wt0   = (const float*)d_in[3];
  const float* bt0   = (const float*)d_in[4];
  const float* wall1 = (const float*)d_in[5];
  const float* ball1 = (const float*)d_in[6];
  const float* wt1   = (const float*)d_in[7];
  const float* bt1   = (const float*)d_in[8];
  float* out = (float*)d_out;
  char* ws = (char*)d_ws;

  if (ws_size < WS_NEED){
    hipMemsetAsync(d_out, 0, (size_t)out_size*4, stream);  // visible failure, no OOB
    return;
  }

  unsigned short* xpk = (unsigned short*)(ws + XPK_OFF);
  unsigned short* wl0 = (unsigned short*)(ws + WL0_OFF);
  unsigned short* wl1 = (unsigned short*)(ws + WL1_OFF);
  unsigned short* h0p = (unsigned short*)(ws + H0_OFF);
  unsigned short* h1p = (unsigned short*)(ws + H1_OFF);
  float* c0 = (float*)(ws + C0_OFF);
  float* c1 = (float*)(ws + C1_OFF);

  k_pack_x<<<16384, 256, 0, stream>>>(x, xpk);
  k_pack_w<<<5120, 256, 0, stream>>>(wall0, wt0, wl0, 0);
  k_pack_w<<<5120, 256, 0, stream>>>(wall1, wt1, wl1, 1);

  for (int s = 0; s <= 512; ++s){
    k_step<<<128, 512, 0, stream>>>(xpk, wl0, wl1, h0p, h1p, c0, c1,
                                    ball0, bt0, ball1, bt1, out, s);
  }
}